// Round 7
// baseline (788.662 us; speedup 1.0000x reference)
//
#include <hip/hip_runtime.h>

#define N_NODES 50000
#define N_EDGES 800000
#define FEATS 128
#define GRID_B 512
#define GM 64
#define TILES_P0 782          // ceil(50000/64)
#define NTILES 1564           // plane0 (q+v) + plane1 (k)
#define NF_WAVES 2048         // GRID_B * 4

typedef __attribute__((ext_vector_type(8))) short bf16x8;
typedef __attribute__((ext_vector_type(4))) float f32x4;

__device__ __forceinline__ unsigned short f2bf(float f){
  unsigned u = __float_as_uint(f);
  u += 0x7FFF + ((u >> 16) & 1);           // RNE
  return (unsigned short)(u >> 16);
}
// bf16 pair unpack, 1 VALU op per float
__device__ __forceinline__ void unpack8(uint4 p, float* f){
  f[0]=__uint_as_float(p.x << 16); f[1]=__uint_as_float(p.x & 0xffff0000u);
  f[2]=__uint_as_float(p.y << 16); f[3]=__uint_as_float(p.y & 0xffff0000u);
  f[4]=__uint_as_float(p.z << 16); f[5]=__uint_as_float(p.z & 0xffff0000u);
  f[6]=__uint_as_float(p.w << 16); f[7]=__uint_as_float(p.w & 0xffff0000u);
}

// grid barrier, normal launch. bar zeroed by host-side memsetAsync before the
// kernel; each phase p uses a fresh (cnt,flag) pair -> no reset/generation.
// Safe because grid (512) <= guaranteed residency (>=2 blocks/CU * 256 CU).
__device__ __forceinline__ void gbar(int* bar, int p, int nb){
  __syncthreads();
  if (threadIdx.x == 0){
    int* cnt = bar + 2*p;
    int* flg = cnt + 1;
    __threadfence();   // release: drain our writes to device scope
    int arrived = __hip_atomic_fetch_add(cnt, 1, __ATOMIC_ACQ_REL, __HIP_MEMORY_SCOPE_AGENT);
    if (arrived == nb - 1){
      __hip_atomic_store(flg, 1, __ATOMIC_RELEASE, __HIP_MEMORY_SCOPE_AGENT);
    } else {
      while (__hip_atomic_load(flg, __ATOMIC_ACQUIRE, __HIP_MEMORY_SCOPE_AGENT) == 0)
        __builtin_amdgcn_s_sleep(1);
    }
    __threadfence();   // acquire: invalidate L1 before re-reading shared data
  }
  __syncthreads();
}

// one 64-row GEMM tile; t < TILES_P0: q+v from ftq (2 B-passes share reg-A); else k from ftk
__device__ __forceinline__ void gemm_tile(int t,
    const float* __restrict__ ftq, const float* __restrict__ ftk,
    const unsigned short* __restrict__ Wball, const float* __restrict__ biasall,
    unsigned short* __restrict__ qv, unsigned short* __restrict__ kb,
    unsigned short (*Bs)[136]){
  int tid = threadIdx.x;
  int wave = tid >> 6, lane = tid & 63;
  int mrow = lane & 15, quad = lane >> 4;
  int plane = (t >= TILES_P0) ? 1 : 0;
  int row0 = (plane ? (t - TILES_P0) : t) * GM;
  const float* X = plane ? ftk : ftq;
  int arow = row0 + wave*16 + mrow;
  bool rok = arow < N_NODES;
  size_t abase = (size_t)(rok ? arow : 0) * FEATS;
  bf16x8 afrag[4];
  #pragma unroll
  for (int kt = 0; kt < 4; kt++){
    const float* xp = X + abase + kt*32 + quad*8;
    float4 x0 = *(const float4*)xp;
    float4 x1 = *(const float4*)(xp + 4);
    if (!rok){ x0 = make_float4(0.f,0.f,0.f,0.f); x1 = x0; }
    bf16x8 a;
    a[0]=(short)f2bf(x0.x); a[1]=(short)f2bf(x0.y); a[2]=(short)f2bf(x0.z); a[3]=(short)f2bf(x0.w);
    a[4]=(short)f2bf(x1.x); a[5]=(short)f2bf(x1.y); a[6]=(short)f2bf(x1.z); a[7]=(short)f2bf(x1.w);
    afrag[kt] = a;
  }
  int mfirst = plane ? 2 : 0;
  int mlast  = plane ? 2 : 1;
  for (int m = mfirst; m <= mlast; m++){
    { // stage B (bf16, dwordx4; stride-17-chunk rows -> 2-way = free)
      const uint4* srcp = (const uint4*)(Wball + m*FEATS*FEATS);
      for (int idx = tid; idx < FEATS*FEATS/8; idx += 256){
        int n = idx >> 4;
        int kk = (idx & 15) * 8;
        *(uint4*)&Bs[n][kk] = srcp[idx];
      }
    }
    __syncthreads();
    f32x4 acc[8];
    #pragma unroll
    for (int i = 0; i < 8; i++) acc[i] = (f32x4){0.f,0.f,0.f,0.f};
    #pragma unroll
    for (int kt = 0; kt < 4; kt++){
      int kbk = kt*32 + quad*8;
      #pragma unroll
      for (int ct = 0; ct < 8; ct++){
        bf16x8 b = *(bf16x8*)&Bs[ct*16 + mrow][kbk];
        acc[ct] = __builtin_amdgcn_mfma_f32_16x16x32_bf16(afrag[kt], b, acc[ct], 0, 0, 0);
      }
    }
    unsigned short* Out = (m==2) ? kb : (qv + m*128);
    const int ostride = (m==2) ? FEATS : 256;
    const float* bias = biasall + m*FEATS;
    #pragma unroll
    for (int ct = 0; ct < 8; ct++){
      int col = ct*16 + mrow;
      float bv = bias[col];
      #pragma unroll
      for (int v = 0; v < 4; v++){
        int orow = row0 + wave*16 + quad*4 + v;
        unsigned ub = f2bf(acc[ct][v] + bv);
        unsigned partner = (unsigned)__shfl_xor((int)ub, 1);
        if (!(mrow & 1) && orow < N_NODES)
          *(unsigned*)&Out[(size_t)orow*ostride + col] = ub | (partner << 16);
      }
    }
    __syncthreads();   // Bs reads done before restage / next tile
  }
}

// ---------------- the whole pipeline as ONE normally-launched persistent kernel
__global__ __launch_bounds__(256, 4) void mega_kernel(
    const float* __restrict__ ftq, const float* __restrict__ ftk,
    const int* __restrict__ srcE, const int* __restrict__ dstE,
    const float* __restrict__ Wq, const float* __restrict__ bq,
    const float* __restrict__ Wk, const float* __restrict__ Wv,
    const float* __restrict__ attn, const float* __restrict__ gq,
    const float* __restrict__ bqn, const float* __restrict__ gk,
    const float* __restrict__ bkn,
    int* __restrict__ bar, int* __restrict__ counts, int* __restrict__ cursor,
    float* __restrict__ sums, int* __restrict__ loc, int* __restrict__ bsums,
    int* __restrict__ bscan, int* __restrict__ src_csr,
    unsigned short* __restrict__ Wb, float* __restrict__ biasf,
    unsigned short* __restrict__ qv, unsigned short* __restrict__ kb,
    float* __restrict__ out){
  __shared__ alignas(16) unsigned char smem[34816];   // union: red(2KB)/scan(4KB)/Bs(34.8KB)
  int tid = threadIdx.x;
  int bid = blockIdx.x;

  // ---- A: BN column stats (blocks 0..255) || dst histogram (256..511)
  if (bid < 256){
    float* red = (float*)smem;                 // [4][128]
    for (int i = tid; i < 4*FEATS; i += 256) red[i] = 0.f;
    __syncthreads();
    int c = tid & 127, half = tid >> 7;
    float sq=0.f, qq=0.f, sk=0.f, kk2=0.f;
    for (int r = bid*2 + half; r < N_NODES; r += 512){
      float xq = ftq[(size_t)r*FEATS + c];
      float xk = ftk[(size_t)r*FEATS + c];
      sq += xq; qq += xq*xq; sk += xk; kk2 += xk*xk;
    }
    atomicAdd(&red[0*FEATS+c], sq);
    atomicAdd(&red[1*FEATS+c], qq);
    atomicAdd(&red[2*FEATS+c], sk);
    atomicAdd(&red[3*FEATS+c], kk2);
    __syncthreads();
    if (tid < FEATS){
      atomicAdd(&sums[0*FEATS+tid], red[0*FEATS+tid]);
      atomicAdd(&sums[1*FEATS+tid], red[1*FEATS+tid]);
      atomicAdd(&sums[2*FEATS+tid], red[2*FEATS+tid]);
      atomicAdd(&sums[3*FEATS+tid], red[3*FEATS+tid]);
    }
  } else {
    for (int t = (bid-256)*256 + tid; t < N_EDGES; t += 256*256)
      atomicAdd(&counts[dstE[t]], 1);
  }
  gbar(bar, 0, GRID_B);

  // ---- B: 256-chunk local scans (0..207) || BN-fold into bf16 weights (208..303)
  if (bid < 208){
    int* s = (int*)smem;
    int i = bid*256 + tid;
    int v = counts[i];                          // zero-padded past 50000
    s[tid] = v; __syncthreads();
    for (int d = 1; d < 256; d <<= 1){
      int tv = (tid >= d) ? s[tid-d] : 0; __syncthreads();
      s[tid] += tv; __syncthreads();
    }
    loc[i] = s[tid] - v;                        // chunk-local exclusive
    if (tid == 255) bsums[bid] = s[255];
  } else if (bid < 304){
    int wv = (bid-208)*4 + (tid >> 6);          // 0..383
    int lane = tid & 63;
    int m = wv >> 7;                            // 0=q,1=v,2=k
    int o = wv & 127;
    const float* Wsrc = (m==0) ? Wq : (m==1) ? Wv : Wk;
    const float* g   = (m==2) ? gk : gq;
    const float* bb  = (m==2) ? bkn : bqn;
    const float* s0  = (m==2) ? (sums + 2*FEATS) : sums;
    const float invN = 1.0f / (float)N_NODES;
    float acc = 0.f;
    unsigned short w2[2];
    int i0 = lane*2;
    #pragma unroll
    for (int t = 0; t < 2; t++){
      int i = i0 + t;
      float mean = s0[i]*invN;
      float var  = s0[FEATS+i]*invN - mean*mean;
      float rstd = rsqrtf(var + 1e-5f);
      float scale = g[i]*rstd;
      float shift = bb[i] - mean*scale;
      float w = Wsrc[o*FEATS + i];
      w2[t] = f2bf(w*scale);
      acc += shift*w;
    }
    ((unsigned*)Wb)[(m*FEATS*FEATS + o*FEATS + i0) >> 1] =
        (unsigned)w2[0] | ((unsigned)w2[1] << 16);
    #pragma unroll
    for (int off = 1; off < 64; off <<= 1) acc += __shfl_xor(acc, off);
    if (lane == 0) biasf[m*FEATS + o] = acc + ((m==0) ? bq[o] : 0.f);
  }
  gbar(bar, 1, GRID_B);

  // ---- C+D: block0 scans the 208 chunk sums (bscan), then all blocks run GEMM tiles
  if (bid == 0){
    int* s = (int*)smem;
    int v = (tid < 208) ? bsums[tid] : 0;
    s[tid] = v; __syncthreads();
    for (int d = 1; d < 256; d <<= 1){
      int tv = (tid >= d) ? s[tid-d] : 0; __syncthreads();
      s[tid] += tv; __syncthreads();
    }
    if (tid < 208) bscan[tid] = s[tid] - v;
    __syncthreads();                            // smem reuse (scan -> Bs)
  }
  for (int t = bid; t < NTILES; t += GRID_B)
    gemm_tile(t, ftq, ftk, Wb, biasf, qv, kb, (unsigned short (*)[136])smem);
  gbar(bar, 2, GRID_B);

  // ---- E: CSR scatter; offset(i) = loc[i] + bscan[i>>8]
  for (int t = bid*256 + tid; t < N_EDGES; t += GRID_B*256){
    int d = dstE[t];
    int p = atomicAdd(&cursor[d], 1);
    src_csr[loc[d] + bscan[d>>8] + p] = srcE[t];
  }
  gbar(bar, 3, GRID_B);

  // ---- F: per-dst-node scores + max-free softmax agg (2048 persistent waves)
  {
    int lane = tid & 63;
    int h = lane & 7, g = lane >> 3;
    int w = bid*4 + (tid >> 6);
    const float L2E = 1.44269504f;
    float ar[16];
    {
      const uint4* ap = (const uint4*)(attn + h*16);
      uint4 a0 = ap[0], a1 = ap[1], a2 = ap[2], a3 = ap[3];
      ar[0]=__uint_as_float(a0.x); ar[1]=__uint_as_float(a0.y); ar[2]=__uint_as_float(a0.z); ar[3]=__uint_as_float(a0.w);
      ar[4]=__uint_as_float(a1.x); ar[5]=__uint_as_float(a1.y); ar[6]=__uint_as_float(a1.z); ar[7]=__uint_as_float(a1.w);
      ar[8]=__uint_as_float(a2.x); ar[9]=__uint_as_float(a2.y); ar[10]=__uint_as_float(a2.z); ar[11]=__uint_as_float(a2.w);
      ar[12]=__uint_as_float(a3.x); ar[13]=__uint_as_float(a3.y); ar[14]=__uint_as_float(a3.z); ar[15]=__uint_as_float(a3.w);
    }
    for (int n = w; n < N_NODES; n += NF_WAVES){
      int off0 = loc[n]   + bscan[n>>8];
      int off1 = loc[n+1] + bscan[(n+1)>>8];    // loc[50000] written by chunk 195
      int deg = off1 - off0;
      if (deg == 0){
        ((float2*)(out + (size_t)n*FEATS))[lane] = make_float2(0.f, 0.f);
        continue;
      }
      float kf2[16];
      {
        const unsigned short* kr = kb + (size_t)n*FEATS + h*16;
        uint4 k0 = *(const uint4*)kr;
        uint4 k1 = *(const uint4*)(kr + 8);
        float kf[16]; unpack8(k0, kf); unpack8(k1, kf+8);
        #pragma unroll
        for (int i = 0; i < 16; i++) kf2[i] = -L2E * kf[i];
      }
      float ssum = 0.f;
      float acc[16];
      #pragma unroll
      for (int i = 0; i < 16; i++) acc[i] = 0.f;
      int s_next = (g < deg) ? src_csr[off0 + g] : 0;
      for (int j = g; j < deg; j += 8){
        int s = s_next;
        if (j + 8 < deg) s_next = src_csr[off0 + j + 8];
        const unsigned short* qr = qv + (size_t)s*256 + h*16;
        uint4 q0 = *(const uint4*)qr;
        uint4 q1 = *(const uint4*)(qr + 8);
        uint4 v0 = *(const uint4*)(qr + 128);   // v half of interleaved row
        uint4 v1 = *(const uint4*)(qr + 136);
        float qf[16]; unpack8(q0, qf); unpack8(q1, qf+8);
        float t = 0.f;
        #pragma unroll
        for (int i = 0; i < 16; i++){
          float xs = fmaf(qf[i], -L2E, kf2[i]);
          float sg = __builtin_amdgcn_rcpf(1.f + __builtin_amdgcn_exp2f(xs));
          t = fmaf(ar[i], sg, t);
        }
        float ex = __builtin_amdgcn_exp2f(t * L2E);  // |t|<=sum|attn| -> max-free safe
        ssum += ex;
        float vf[16]; unpack8(v0, vf); unpack8(v1, vf+8);
        #pragma unroll
        for (int i = 0; i < 16; i++) acc[i] = fmaf(ex, vf[i], acc[i]);
      }
      ssum += __shfl_xor(ssum, 8); ssum += __shfl_xor(ssum, 16); ssum += __shfl_xor(ssum, 32);
      #pragma unroll
      for (int i = 0; i < 16; i++){
        acc[i] += __shfl_xor(acc[i], 8);
        acc[i] += __shfl_xor(acc[i], 16);
        acc[i] += __shfl_xor(acc[i], 32);
      }
      if (g == 0){
        float inv_s = 1.f / ssum;
        float4* op = (float4*)(out + (size_t)n*FEATS + h*16);
        op[0] = make_float4(acc[0]*inv_s, acc[1]*inv_s, acc[2]*inv_s, acc[3]*inv_s);
        op[1] = make_float4(acc[4]*inv_s, acc[5]*inv_s, acc[6]*inv_s, acc[7]*inv_s);
        op[2] = make_float4(acc[8]*inv_s, acc[9]*inv_s, acc[10]*inv_s, acc[11]*inv_s);
        op[3] = make_float4(acc[12]*inv_s, acc[13]*inv_s, acc[14]*inv_s, acc[15]*inv_s);
      }
    }
  }
}

extern "C" void kernel_launch(void* const* d_in, const int* in_sizes, int n_in,
                              void* d_out, int out_size, void* d_ws, size_t ws_size,
                              hipStream_t stream){
  (void)in_sizes; (void)n_in; (void)out_size; (void)ws_size;
  const float* ftq  = (const float*)d_in[0];
  const float* ftk  = (const float*)d_in[1];
  const int*   srcE = (const int*)d_in[2];
  const int*   dstE = (const int*)d_in[3];
  const float* Wq   = (const float*)d_in[4];
  const float* bq   = (const float*)d_in[5];
  const float* Wk   = (const float*)d_in[6];
  const float* Wv   = (const float*)d_in[7];
  const float* attn = (const float*)d_in[8];
  const float* gq   = (const float*)d_in[9];
  const float* bqn  = (const float*)d_in[10];
  const float* gk   = (const float*)d_in[11];
  const float* bkn  = (const float*)d_in[12];

  char* ws = (char*)d_ws;
  int*   bar     = (int*)(ws + 0);             // 16 ints (8 barrier pairs)
  int*   counts  = (int*)(ws + 64);            // 53248 ints (padded for chunk scan)
  int*   cursor  = (int*)(ws + 213056);        // 50000 ints
  float* sums    = (float*)(ws + 413056);      // 512 f   (zero region = [0,415104))
  int*   loc     = (int*)(ws + 415104);        // 53248 ints (chunk-local offsets)
  int*   bsums   = (int*)(ws + 628096);        // 256 ints
  int*   bscan   = (int*)(ws + 629120);        // 256 ints
  int*   src_csr = (int*)(ws + 630144);        // 800000 ints
  unsigned short* Wb = (unsigned short*)(ws + 3830144);  // 3*128*128 bf16
  float* biasf   = (float*)(ws + 3928448);     // 384 f
  unsigned short* qv = (unsigned short*)(ws + 3929984);  // 50000*256 bf16 (q|v interleaved)
  unsigned short* kb = qv + (size_t)N_NODES*256;         // 50000*128 bf16
  float* out = (float*)d_out;

  hipMemsetAsync(ws, 0, 415104, stream);  // bar, counts, cursor, sums

  hipLaunchKernelGGL(mega_kernel, dim3(GRID_B), dim3(256), 0, stream,
                     ftq, ftk, srcE, dstE, Wq, bq, Wk, Wv, attn, gq, bqn, gk, bkn,
                     bar, counts, cursor, sums, loc, bsums, bscan, src_csr,
                     Wb, biasf, qv, kb, out);
}

// Round 8
// 290.041 us; speedup vs baseline: 2.7191x; 2.7191x over previous
//
#include <hip/hip_runtime.h>

#define N_NODES 50000
#define N_EDGES 800000
#define FEATS 128
#define NCHUNK 196            // ceil(50000/256)
#define CPAD 50176            // NCHUNK*256 (counts/loc padded, zeroed)
#define GEMM_BX 196
#define GEMM_BLOCKS 588       // 3 planes x 196
#define SCAT_BLOCKS 3125      // 3125*256 = 800000 exactly
#define NTILE 782             // ceil(50000/64)
#define NF_WAVES 8192

typedef __attribute__((ext_vector_type(8))) short bf16x8;
typedef __attribute__((ext_vector_type(4))) float f32x4;

__device__ __forceinline__ unsigned short f2bf(float f){
  unsigned u = __float_as_uint(f);
  u += 0x7FFF + ((u >> 16) & 1);           // RNE
  return (unsigned short)(u >> 16);
}
// bf16 pair unpack, 1 VALU op per float
__device__ __forceinline__ void unpack8(uint4 p, float* f){
  f[0]=__uint_as_float(p.x << 16); f[1]=__uint_as_float(p.x & 0xffff0000u);
  f[2]=__uint_as_float(p.y << 16); f[3]=__uint_as_float(p.y & 0xffff0000u);
  f[4]=__uint_as_float(p.z << 16); f[5]=__uint_as_float(p.z & 0xffff0000u);
  f[6]=__uint_as_float(p.w << 16); f[7]=__uint_as_float(p.w & 0xffff0000u);
}

// ---------------- dispatch 1: BN stats (blocks 0..767) || dst hist + chunk sums (768..1023)
__global__ __launch_bounds__(256) void stats_hist_kernel(
    const float* __restrict__ ftq, const float* __restrict__ ftk,
    float* __restrict__ sums, const int* __restrict__ dstE,
    int* __restrict__ counts, int* __restrict__ csums){
  __shared__ float red[4*FEATS];
  __shared__ int lchunk[NCHUNK];
  int tid = threadIdx.x, bid = blockIdx.x;
  if (bid < 768){
    for (int i = tid; i < 4*FEATS; i += 256) red[i] = 0.f;
    __syncthreads();
    int c = tid & 127, half = tid >> 7;
    float sq=0.f, qq=0.f, sk=0.f, kk2=0.f;
    for (int r = bid*2 + half; r < N_NODES; r += 1536){
      float xq = ftq[(size_t)r*FEATS + c];
      float xk = ftk[(size_t)r*FEATS + c];
      sq += xq; qq += xq*xq; sk += xk; kk2 += xk*xk;
    }
    atomicAdd(&red[0*FEATS+c], sq);
    atomicAdd(&red[1*FEATS+c], qq);
    atomicAdd(&red[2*FEATS+c], sk);
    atomicAdd(&red[3*FEATS+c], kk2);
    __syncthreads();
    if (tid < FEATS){
      atomicAdd(&sums[0*FEATS+tid], red[0*FEATS+tid]);
      atomicAdd(&sums[1*FEATS+tid], red[1*FEATS+tid]);
      atomicAdd(&sums[2*FEATS+tid], red[2*FEATS+tid]);
      atomicAdd(&sums[3*FEATS+tid], red[3*FEATS+tid]);
    }
  } else {
    for (int i = tid; i < NCHUNK; i += 256) lchunk[i] = 0;
    __syncthreads();
    for (int t = (bid-768)*256 + tid; t < N_EDGES; t += 256*256){
      int d = dstE[t];
      atomicAdd(&counts[d], 1);
      atomicAdd(&lchunk[d >> 8], 1);
    }
    __syncthreads();
    for (int i = tid; i < NCHUNK; i += 256)
      if (lchunk[i]) atomicAdd(&csums[i], lchunk[i]);
  }
}

// ---------------- dispatch 2: chunk-local scans (0..195) || csums scan (196) || BN-fold (197..292)
__global__ __launch_bounds__(256) void scan_fold_kernel(
    const int* __restrict__ counts, const int* __restrict__ csums,
    int* __restrict__ loc, int* __restrict__ bscan,
    const float* __restrict__ Wq, const float* __restrict__ bq,
    const float* __restrict__ Wk, const float* __restrict__ Wv,
    const float* __restrict__ gq, const float* __restrict__ bqn,
    const float* __restrict__ gk, const float* __restrict__ bkn,
    const float* __restrict__ sums,
    unsigned short* __restrict__ Wb, float* __restrict__ bias){
  __shared__ int s[256];
  int tid = threadIdx.x, bid = blockIdx.x;
  if (bid < NCHUNK){
    int i = bid*256 + tid;
    int v = counts[i];                          // padded region is zero
    s[tid] = v; __syncthreads();
    for (int d = 1; d < 256; d <<= 1){
      int tv = (tid >= d) ? s[tid-d] : 0; __syncthreads();
      s[tid] += tv; __syncthreads();
    }
    loc[i] = s[tid] - v;                        // chunk-local exclusive
  } else if (bid == NCHUNK){
    int v = (tid < NCHUNK) ? csums[tid] : 0;
    s[tid] = v; __syncthreads();
    for (int d = 1; d < 256; d <<= 1){
      int tv = (tid >= d) ? s[tid-d] : 0; __syncthreads();
      s[tid] += tv; __syncthreads();
    }
    if (tid < NCHUNK) bscan[tid] = s[tid] - v;  // exclusive chunk bases
  } else {
    int wv = (bid - NCHUNK - 1)*4 + (tid >> 6); // 0..383
    int lane = tid & 63;
    int m = wv >> 7;                            // 0=q,1=v,2=k
    int o = wv & 127;
    const float* Wsrc = (m==0) ? Wq : (m==1) ? Wv : Wk;
    const float* g   = (m==2) ? gk : gq;
    const float* bb  = (m==2) ? bkn : bqn;
    const float* s0  = (m==2) ? (sums + 2*FEATS) : sums;
    const float invN = 1.0f / (float)N_NODES;
    float acc = 0.f;
    unsigned short w2[2];
    int i0 = lane*2;
    #pragma unroll
    for (int t = 0; t < 2; t++){
      int i = i0 + t;
      float mean = s0[i]*invN;
      float var  = s0[FEATS+i]*invN - mean*mean;
      float rstd = rsqrtf(var + 1e-5f);
      float scale = g[i]*rstd;
      float shift = bb[i] - mean*scale;
      float w = Wsrc[o*FEATS + i];
      w2[t] = f2bf(w*scale);
      acc += shift*w;
    }
    ((unsigned*)Wb)[(m*FEATS*FEATS + o*FEATS + i0) >> 1] =
        (unsigned)w2[0] | ((unsigned)w2[1] << 16);
    #pragma unroll
    for (int off = 1; off < 64; off <<= 1) acc += __shfl_xor(acc, off);
    if (lane == 0) bias[m*FEATS + o] = acc + ((m==0) ? bq[o] : 0.f);
  }
}

// ---------------- dispatch 3: persistent-B GEMM (blocks 0..587) || CSR scatter (588..3712)
__global__ __launch_bounds__(256) void gemm_scatter_kernel(
    const float* __restrict__ ftq, const float* __restrict__ ftk,
    const unsigned short* __restrict__ Wball, const float* __restrict__ biasall,
    unsigned short* __restrict__ qv, unsigned short* __restrict__ kb,
    const int* __restrict__ dstE, const int* __restrict__ srcE,
    const int* __restrict__ loc, const int* __restrict__ bscan,
    int* __restrict__ cursor, int* __restrict__ src_csr){
  __shared__ unsigned short Bs[FEATS][136];
  int tid = threadIdx.x, bid = blockIdx.x;
  if (bid >= GEMM_BLOCKS){
    int t = (bid - GEMM_BLOCKS)*256 + tid;     // exactly covers N_EDGES
    int d = dstE[t];
    int p = atomicAdd(&cursor[d], 1);
    src_csr[loc[d] + bscan[d >> 8] + p] = srcE[t];
    return;
  }
  int m = bid / GEMM_BX;                        // 0=q,1=v,2=k
  int bx = bid - m*GEMM_BX;
  const float* X = (m==2) ? ftk : ftq;
  { // stage this plane's B ONCE (dwordx4; stride-17-chunk rows -> 2-way = free)
    const uint4* srcp = (const uint4*)(Wball + m*FEATS*FEATS);
    for (int idx = tid; idx < FEATS*FEATS/8; idx += 256){
      int n = idx >> 4;
      int kk = (idx & 15) * 8;
      *(uint4*)&Bs[n][kk] = srcp[idx];
    }
  }
  __syncthreads();                              // only barrier in the kernel
  int wave = tid >> 6, lane = tid & 63;
  int mrow = lane & 15, quad = lane >> 4;
  unsigned short* Out = (m==2) ? kb : (qv + m*128);
  const int ostride = (m==2) ? FEATS : 256;
  float bv[8];
  #pragma unroll
  for (int ct = 0; ct < 8; ct++) bv[ct] = biasall[m*FEATS + ct*16 + mrow];
  for (int t = bx; t < NTILE; t += GEMM_BX){
    int row0 = t*64;
    int arow = row0 + wave*16 + mrow;
    bool rok = arow < N_NODES;
    size_t abase = (size_t)(rok ? arow : 0) * FEATS;
    bf16x8 afrag[4];
    #pragma unroll
    for (int kt = 0; kt < 4; kt++){
      const float* xp = X + abase + kt*32 + quad*8;
      float4 x0 = *(const float4*)xp;
      float4 x1 = *(const float4*)(xp + 4);
      if (!rok){ x0 = make_float4(0.f,0.f,0.f,0.f); x1 = x0; }
      bf16x8 a;
      a[0]=(short)f2bf(x0.x); a[1]=(short)f2bf(x0.y); a[2]=(short)f2bf(x0.z); a[3]=(short)f2bf(x0.w);
      a[4]=(short)f2bf(x1.x); a[5]=(short)f2bf(x1.y); a[6]=(short)f2bf(x1.z); a[7]=(short)f2bf(x1.w);
      afrag[kt] = a;
    }
    f32x4 acc[8];
    #pragma unroll
    for (int i = 0; i < 8; i++) acc[i] = (f32x4){0.f,0.f,0.f,0.f};
    #pragma unroll
    for (int kt = 0; kt < 4; kt++){
      int kbk = kt*32 + quad*8;
      #pragma unroll
      for (int ct = 0; ct < 8; ct++){
        bf16x8 b = *(bf16x8*)&Bs[ct*16 + mrow][kbk];
        acc[ct] = __builtin_amdgcn_mfma_f32_16x16x32_bf16(afrag[kt], b, acc[ct], 0, 0, 0);
      }
    }
    #pragma unroll
    for (int ct = 0; ct < 8; ct++){
      int col = ct*16 + mrow;
      #pragma unroll
      for (int v = 0; v < 4; v++){
        int orow = row0 + wave*16 + quad*4 + v;
        unsigned ub = f2bf(acc[ct][v] + bv[ct]);
        unsigned partner = (unsigned)__shfl_xor((int)ub, 1);
        if (!(mrow & 1) && orow < N_NODES)
          *(unsigned*)&Out[(size_t)orow*ostride + col] = ub | (partner << 16);
      }
    }
  }
}

// ---------------- dispatch 4: per-dst-node scores + max-free softmax agg (8192 waves)
__global__ __launch_bounds__(256) void node_fused_kernel(
    const unsigned short* __restrict__ qv, const unsigned short* __restrict__ kb,
    const float* __restrict__ attn, const int* __restrict__ src_csr,
    const int* __restrict__ loc, const int* __restrict__ bscan,
    float* __restrict__ out){
  int tid = threadIdx.x;
  int lane = tid & 63;
  int h = lane & 7, g = lane >> 3;
  int w = blockIdx.x*4 + (tid >> 6);
  const float L2E = 1.44269504f;
  float ar[16];
  {
    const uint4* ap = (const uint4*)(attn + h*16);
    uint4 a0 = ap[0], a1 = ap[1], a2 = ap[2], a3 = ap[3];
    ar[0]=__uint_as_float(a0.x); ar[1]=__uint_as_float(a0.y); ar[2]=__uint_as_float(a0.z); ar[3]=__uint_as_float(a0.w);
    ar[4]=__uint_as_float(a1.x); ar[5]=__uint_as_float(a1.y); ar[6]=__uint_as_float(a1.z); ar[7]=__uint_as_float(a1.w);
    ar[8]=__uint_as_float(a2.x); ar[9]=__uint_as_float(a2.y); ar[10]=__uint_as_float(a2.z); ar[11]=__uint_as_float(a2.w);
    ar[12]=__uint_as_float(a3.x); ar[13]=__uint_as_float(a3.y); ar[14]=__uint_as_float(a3.z); ar[15]=__uint_as_float(a3.w);
  }
  for (int n = w; n < N_NODES; n += NF_WAVES){
    int off0 = loc[n]   + bscan[n>>8];
    int off1 = loc[n+1] + bscan[(n+1)>>8];      // loc[50000] valid (padded chunk 195)
    int deg = off1 - off0;
    if (deg == 0){
      ((float2*)(out + (size_t)n*FEATS))[lane] = make_float2(0.f, 0.f);
      continue;
    }
    float kf2[16];
    {
      const unsigned short* kr = kb + (size_t)n*FEATS + h*16;
      uint4 k0 = *(const uint4*)kr;
      uint4 k1 = *(const uint4*)(kr + 8);
      float kf[16]; unpack8(k0, kf); unpack8(k1, kf+8);
      #pragma unroll
      for (int i = 0; i < 16; i++) kf2[i] = -L2E * kf[i];
    }
    float ssum = 0.f;
    float acc[16];
    #pragma unroll
    for (int i = 0; i < 16; i++) acc[i] = 0.f;
    int s_next = (g < deg) ? src_csr[off0 + g] : 0;
    for (int j = g; j < deg; j += 8){
      int s = s_next;
      if (j + 8 < deg) s_next = src_csr[off0 + j + 8];
      const unsigned short* qr = qv + (size_t)s*256 + h*16;
      uint4 q0 = *(const uint4*)qr;
      uint4 q1 = *(const uint4*)(qr + 8);
      uint4 v0 = *(const uint4*)(qr + 128);     // v half of interleaved row
      uint4 v1 = *(const uint4*)(qr + 136);
      float qf[16]; unpack8(q0, qf); unpack8(q1, qf+8);
      float t = 0.f;
      #pragma unroll
      for (int i = 0; i < 16; i++){
        float xs = fmaf(qf[i], -L2E, kf2[i]);
        float sg = __builtin_amdgcn_rcpf(1.f + __builtin_amdgcn_exp2f(xs));
        t = fmaf(ar[i], sg, t);
      }
      float ex = __builtin_amdgcn_exp2f(t * L2E);   // |t|<=sum|attn| -> max-free safe
      ssum += ex;
      float vf[16]; unpack8(v0, vf); unpack8(v1, vf+8);
      #pragma unroll
      for (int i = 0; i < 16; i++) acc[i] = fmaf(ex, vf[i], acc[i]);
    }
    ssum += __shfl_xor(ssum, 8); ssum += __shfl_xor(ssum, 16); ssum += __shfl_xor(ssum, 32);
    #pragma unroll
    for (int i = 0; i < 16; i++){
      acc[i] += __shfl_xor(acc[i], 8);
      acc[i] += __shfl_xor(acc[i], 16);
      acc[i] += __shfl_xor(acc[i], 32);
    }
    if (g == 0){
      float inv_s = 1.f / ssum;
      float4* op = (float4*)(out + (size_t)n*FEATS + h*16);
      op[0] = make_float4(acc[0]*inv_s, acc[1]*inv_s, acc[2]*inv_s, acc[3]*inv_s);
      op[1] = make_float4(acc[4]*inv_s, acc[5]*inv_s, acc[6]*inv_s, acc[7]*inv_s);
      op[2] = make_float4(acc[8]*inv_s, acc[9]*inv_s, acc[10]*inv_s, acc[11]*inv_s);
      op[3] = make_float4(acc[12]*inv_s, acc[13]*inv_s, acc[14]*inv_s, acc[15]*inv_s);
    }
  }
}

extern "C" void kernel_launch(void* const* d_in, const int* in_sizes, int n_in,
                              void* d_out, int out_size, void* d_ws, size_t ws_size,
                              hipStream_t stream){
  (void)in_sizes; (void)n_in; (void)out_size; (void)ws_size;
  const float* ftq  = (const float*)d_in[0];
  const float* ftk  = (const float*)d_in[1];
  const int*   srcE = (const int*)d_in[2];
  const int*   dstE = (const int*)d_in[3];
  const float* Wq   = (const float*)d_in[4];
  const float* bq   = (const float*)d_in[5];
  const float* Wk   = (const float*)d_in[6];
  const float* Wv   = (const float*)d_in[7];
  const float* attn = (const float*)d_in[8];
  const float* gq   = (const float*)d_in[9];
  const float* bqn  = (const float*)d_in[10];
  const float* gk   = (const float*)d_in[11];
  const float* bkn  = (const float*)d_in[12];

  char* ws = (char*)d_ws;
  int*   counts  = (int*)(ws + 0);             // CPAD ints [0, 200704)
  int*   cursor  = (int*)(ws + 200704);        // 50000 ints [200704, 400704)
  float* sums    = (float*)(ws + 400704);      // 512 f [400704, 402752)
  int*   csums   = (int*)(ws + 402752);        // 196 ints [402752, 403536) <- memset end
  int*   loc     = (int*)(ws + 403536);        // CPAD ints [403536, 604240)
  int*   bscan   = (int*)(ws + 604240);        // 196 ints
  int*   src_csr = (int*)(ws + 605024);        // 800000 ints [605024, 3805024)
  unsigned short* Wb = (unsigned short*)(ws + 3805024);  // 3*128*128 bf16
  float* biasf   = (float*)(ws + 3903328);     // 384 f
  unsigned short* qv = (unsigned short*)(ws + 3904864);  // 50000*256 bf16 (q|v interleaved)
  unsigned short* kb = qv + (size_t)N_NODES*256;         // 50000*128 bf16
  float* out = (float*)d_out;

  hipMemsetAsync(ws, 0, 403536, stream);  // counts, cursor, sums, csums

  hipLaunchKernelGGL(stats_hist_kernel, dim3(1024), dim3(256), 0, stream,
                     ftq, ftk, sums, dstE, counts, csums);
  hipLaunchKernelGGL(scan_fold_kernel, dim3(293), dim3(256), 0, stream,
                     counts, csums, loc, bscan,
                     Wq, bq, Wk, Wv, gq, bqn, gk, bkn, sums, Wb, biasf);
  hipLaunchKernelGGL(gemm_scatter_kernel, dim3(GEMM_BLOCKS + SCAT_BLOCKS), dim3(256), 0, stream,
                     ftq, ftk, Wb, biasf, qv, kb, dstE, srcE, loc, bscan, cursor, src_csr);
  hipLaunchKernelGGL(node_fused_kernel, dim3(NF_WAVES/4), dim3(256), 0, stream,
                     qv, kb, attn, src_csr, loc, bscan, out);
}